// Round 4
// baseline (392.335 us; speedup 1.0000x reference)
//
#include <hip/hip_runtime.h>
#include <hip/hip_fp16.h>

#define C 4096
#define NN 110
#define MPAD 112

typedef _Float16 f16x8 __attribute__((ext_vector_type(8)));
typedef float fx4 __attribute__((ext_vector_type(4)));
typedef unsigned long long ull;

// ---------------------------------------------------------------------------
// prep1: A1[112][4096] = fp16(x), rows >=110 zeroed. u32 pair stores.
// ---------------------------------------------------------------------------
__global__ __launch_bounds__(256)
void prep1_kernel(const float* __restrict__ x, _Float16* __restrict__ A1) {
    int idx = blockIdx.x * 256 + threadIdx.x;     // pair index, 112*2048 total
    int n = idx >> 11;
    union { _Float16 h[2]; unsigned u; } pk;
    pk.u = 0;
    if (n < NN) {
        float2 v = *(const float2*)(x + 2 * (size_t)idx);
        pk.h[0] = (_Float16)v.x;
        pk.h[1] = (_Float16)v.y;
    }
    ((unsigned*)A1)[idx] = pk.u;
}

// ---------------------------------------------------------------------------
// maskprep: once-only adjacency bitmasks + degrees
// ---------------------------------------------------------------------------
__global__ __launch_bounds__(128)
void maskprep_kernel(const int* __restrict__ adj, ull* __restrict__ mlo,
                     ull* __restrict__ mhi, float* __restrict__ degs) {
    int j = threadIdx.x;
    if (j < NN) {
        ull lo = 0, hi = 0; int dg = 0;
        for (int i = 0; i < 64; ++i) {
            int m = (adj[i * NN + j] != 0);
            lo |= ((ull)m) << i; dg += m;
        }
        for (int i = 64; i < NN; ++i) {
            int m = (adj[i * NN + j] != 0);
            hi |= ((ull)m) << (i - 64); dg += m;
        }
        mlo[j] = lo; mhi[j] = hi;
        degs[j] = (float)(dg > 0 ? dg : 1);
    }
}

// ---------------------------------------------------------------------------
// mm: Cacc[0:110,:] += A16[0:112, kchunk] @ fp16(B[kchunk, :])
//  - A-fragments direct from global (L2-resident, frag = 16B run)
//  - B staged regs -> LDS (transpose+cvt), XOR-swizzled 16B granules
//  - T4 pipeline: raw s_barrier with lgkmcnt(0) ONLY — vmcnt never drains
//    in-loop, so chunk it+2's 16 B-loads stay in flight across the barrier.
// Block 256 thr = 4 waves, tile 112(m) x 64(n), wave w -> cols w*16..+15.
// ---------------------------------------------------------------------------
// non-draining barrier: ds-visibility only; VMEM loads stay outstanding.
#define PIPE_BARRIER()                                                \
    do {                                                              \
        asm volatile("s_waitcnt lgkmcnt(0)" ::: "memory");            \
        __builtin_amdgcn_s_barrier();                                 \
        __builtin_amdgcn_sched_barrier(0);                            \
    } while (0)

template<int NITER>
__global__ __launch_bounds__(256, 3)
void mm_kernel(const _Float16* __restrict__ A, const float* __restrict__ B,
               float* __restrict__ Cacc, int lda) {
    __shared__ __align__(16) _Float16 Bs[2][64 * 64];   // [buf][c*64 + swz k]

    const int t   = threadIdx.x;
    const int j0  = blockIdx.x * 64;
    const int k0  = blockIdx.y * (NITER * 64);
    const int w   = t >> 6;
    const int L   = t & 63;
    const int l15 = L & 15;
    const int q   = L >> 4;
    const int sc  = t & 63;        // staging column 0..63
    const int kg  = t >> 6;        // staging k-group (== wave id)
    const int swz = sc & 7;

    fx4 acc[7];
#pragma unroll
    for (int mt = 0; mt < 7; ++mt) acc[mt] = (fx4){0.f, 0.f, 0.f, 0.f};

    const float*    Bp  = B + (size_t)k0 * C + j0 + sc;
    const _Float16* Ap  = A + (size_t)l15 * lda + k0;
    _Float16*       BsW = &Bs[0][0] + sc * 64;
    const _Float16* BsR = &Bs[0][0] + (w * 16 + l15) * 64;

    float bva[16], bvb[16];

#define LOADB(dst, ch)                                                         \
    { _Pragma("unroll")                                                        \
      for (int p = 0; p < 16; ++p)                                             \
          dst[p] = Bp[(size_t)((ch) * 64 + kg * 16 + p) * C]; }

#define COMMITB(src, buf)                                                      \
    { _Pragma("unroll")                                                        \
      for (int p2 = 0; p2 < 2; ++p2) {                                         \
          f16x8 hv;                                                            \
          _Pragma("unroll")                                                    \
          for (int e = 0; e < 8; ++e) hv[e] = (_Float16)src[p2 * 8 + e];       \
          *(f16x8*)(BsW + (buf) * 4096 + (((kg * 2 + p2) ^ swz) << 3)) = hv;   \
      } }

    // prologue: chunk0 -> Bs[0] (one-time vmcnt(0) stall); chunk1 -> bva,
    // left in flight across the non-draining barrier.
    LOADB(bva, 0);
    COMMITB(bva, 0);
    LOADB(bva, 1);
    PIPE_BARRIER();

#pragma unroll
    for (int it = 0; it < NITER; ++it) {
        // A-fragments for this iter (oldest in queue -> MFMA's wait leaves B in flight)
        f16x8 af[2][7];
#pragma unroll
        for (int s = 0; s < 2; ++s)
#pragma unroll
            for (int mt = 0; mt < 7; ++mt)
                af[s][mt] = *(const f16x8*)(Ap + (size_t)mt * 16 * lda
                                            + it * 64 + s * 32 + q * 8);
        __builtin_amdgcn_sched_barrier(0);
        // issue B loads for chunk it+2 (newest; outstanding through MFMA + barrier)
        if (it + 2 < NITER) {
            if (it & 1) { LOADB(bva, it + 2); } else { LOADB(bvb, it + 2); }
        }
        __builtin_amdgcn_sched_barrier(0);
        // MFMA on current buffer (dep-wait retires to vmcnt(16): A done, B(it+2) live)
#pragma unroll
        for (int s = 0; s < 2; ++s) {
            f16x8 bf = *(const f16x8*)(BsR + (it & 1) * 4096
                            + ((((s << 2) + q) ^ (l15 & 7)) << 3));
#pragma unroll
            for (int mt = 0; mt < 7; ++mt)
                acc[mt] = __builtin_amdgcn_mfma_f32_16x16x32_f16(
                    af[s][mt], bf, acc[mt], 0, 0, 0);
        }
        // commit chunk it+1 (regs already retired by MFMA's vmcnt wait)
        if (it + 1 < NITER) {
            if (it & 1) { COMMITB(bvb, (it + 1) & 1); }
            else        { COMMITB(bva, (it + 1) & 1); }
            PIPE_BARRIER();
            // hazard: COMMIT writes buf[(it+1)&1]; its last reader was iter
            // it-1's MFMA, separated by iter it-1's barrier. lgkmcnt(0)
            // before s_barrier publishes the writes; sched_barrier(0) after
            // stops next iter's ds_read hoisting above the barrier.
        }
    }

    // epilogue: fp32 atomic accumulate (C/D: col=lane&15, row=q*4+reg)
    const int col = j0 + w * 16 + l15;
#pragma unroll
    for (int mt = 0; mt < 7; ++mt)
#pragma unroll
        for (int r = 0; r < 4; ++r) {
            int row = mt * 16 + q * 4 + r;
            if (row < NN)
                atomicAdd(&Cacc[(size_t)row * C + col], acc[mt][r]);
        }
#undef LOADB
#undef COMMITB
}

// ---------------------------------------------------------------------------
// agg: per 16-col tile, builds A3 = fp16([h+b2, aggr]) [112][8192], u32 stores
// ---------------------------------------------------------------------------
__global__ __launch_bounds__(256)
void agg_kernel(const float* __restrict__ h_raw, const ull* __restrict__ gmlo,
                const ull* __restrict__ gmhi, const float* __restrict__ gdegs,
                const float* __restrict__ b2, _Float16* __restrict__ A3) {
    __shared__ float hb[NN * 16];
    const int t  = threadIdx.x;
    const int c0 = blockIdx.x * 16;

    for (int idx = t; idx < NN * 8; idx += 256) {
        int n = idx >> 3, cp = (idx & 7) << 1;
        float2 v = *(const float2*)(h_raw + (size_t)n * C + c0 + cp);
        float v0 = v.x + b2[c0 + cp];
        float v1 = v.y + b2[c0 + cp + 1];
        hb[n * 16 + cp]     = v0;
        hb[n * 16 + cp + 1] = v1;
        union { _Float16 h[2]; unsigned u; } pk;
        pk.h[0] = (_Float16)v0;
        pk.h[1] = (_Float16)v1;
        *(unsigned*)(A3 + (size_t)n * (2 * C) + c0 + cp) = pk.u;
    }
    if (t < 32) {
        int n  = NN + (t >> 4);
        int hs = (t >> 3) & 1;
        int cp = (t & 7) << 1;
        *(unsigned*)(A3 + (size_t)n * (2 * C) + hs * C + c0 + cp) = 0u;
    }
    __syncthreads();
    for (int idx = t; idx < NN * 8; idx += 256) {
        int j = idx >> 3, cp = (idx & 7) << 1;
        ull lo = gmlo[j], hi = gmhi[j];
        float dg = gdegs[j];
        float a0 = 0.f, a1 = 0.f;
        for (int i = 0; i < 64; ++i)
            if ((lo >> i) & 1) { a0 += hb[i * 16 + cp]; a1 += hb[i * 16 + cp + 1]; }
        for (int i = 64; i < NN; ++i)
            if ((hi >> (i - 64)) & 1) { a0 += hb[i * 16 + cp]; a1 += hb[i * 16 + cp + 1]; }
        union { _Float16 h[2]; unsigned u; } pk;
        pk.h[0] = (_Float16)(a0 / dg);
        pk.h[1] = (_Float16)(a1 / dg);
        *(unsigned*)(A3 + (size_t)j * (2 * C) + C + c0 + cp) = pk.u;
    }
}

// ---------------------------------------------------------------------------
// fin: out[j,c] = sum_k Wl[j,k] * relu(z_raw[k,c]+b1[c]) + bl[j]
// ---------------------------------------------------------------------------
__global__ __launch_bounds__(256)
void fin_kernel(const float* __restrict__ z_raw, const float* __restrict__ b1,
                const float* __restrict__ Wl, const float* __restrict__ bl,
                float* __restrict__ out) {
    __shared__ float zs[NN * 64];
    const int t  = threadIdx.x;
    const int c0 = blockIdx.x * 64;
    const int c  = t & 63;

    for (int idx = t; idx < NN * 64; idx += 256) {
        int k = idx >> 6, cc = idx & 63;
        float v = z_raw[(size_t)k * C + c0 + cc] + b1[c0 + cc];
        zs[idx] = fmaxf(v, 0.f);
    }
    __syncthreads();
    for (int jj = 0; jj < 7; ++jj) {
        int j = blockIdx.y * 28 + jj * 4 + (t >> 6);
        if (j < NN) {
            float a = bl[j];
#pragma unroll 2
            for (int k = 0; k < NN; ++k)
                a += Wl[j * NN + k] * zs[k * 64 + c];   // Wl wave-uniform -> scalar
            out[(size_t)j * C + c0 + c] = a;
        }
    }
}

// ---------------------------------------------------------------------------
extern "C" void kernel_launch(void* const* d_in, const int* in_sizes, int n_in,
                              void* d_out, int out_size, void* d_ws, size_t ws_size,
                              hipStream_t stream) {
    const float* x   = (const float*)d_in[0];
    const int*   adj = (const int*)d_in[1];
    const float* W2  = (const float*)d_in[2];
    const float* b2  = (const float*)d_in[3];
    const float* W1  = (const float*)d_in[4];
    const float* b1  = (const float*)d_in[5];
    const float* Wl  = (const float*)d_in[6];
    const float* bl  = (const float*)d_in[7];
    float* out = (float*)d_out;

    char* ws = (char*)d_ws;
    float*    h_raw = (float*)(ws);                    // 110*4096 f32
    float*    z_raw = (float*)(ws + 1802240);          // 110*4096 f32
    _Float16* A1    = (_Float16*)(ws + 3604480);       // 112*4096 f16
    _Float16* A3    = (_Float16*)(ws + 4521984);       // 112*8192 f16
    ull*      mlo   = (ull*)(ws + 6356992);            // 110 u64
    ull*      mhi   = (ull*)(ws + 6357872);            // 110 u64
    float*    degs  = (float*)(ws + 6358752);          // 110 f32

    hipMemsetAsync(d_ws, 0, 3604480, stream);                        // zero h_raw,z_raw
    prep1_kernel<<<(MPAD * C / 2) / 256, 256, 0, stream>>>(x, A1);
    maskprep_kernel<<<1, 128, 0, stream>>>(adj, mlo, mhi, degs);
    mm_kernel<4><<<dim3(64, 16), 256, 0, stream>>>(A1, W2, h_raw, C);
    agg_kernel<<<C / 16, 256, 0, stream>>>(h_raw, mlo, mhi, degs, b2, A3);
    mm_kernel<8><<<dim3(64, 16), 256, 0, stream>>>(A3, W1, z_raw, 2 * C);
    fin_kernel<<<dim3(C / 64, 4), 256, 0, stream>>>(z_raw, b1, Wl, bl, out);
}

// Round 5
// 355.470 us; speedup vs baseline: 1.1037x; 1.1037x over previous
//
#include <hip/hip_runtime.h>
#include <hip/hip_fp16.h>

#define C 4096
#define NN 110
#define MPAD 112
#define NMT 7                // m-tiles of 16 (112 rows)
#define KBS (NMT * 512)      // halves per 32-k fragment block = 3584

typedef _Float16 f16x8 __attribute__((ext_vector_type(8)));
typedef float fx4 __attribute__((ext_vector_type(4)));
typedef unsigned long long ull;

// Fragment-major layout for fp16 A operands:
//   idx(n,c) = (c>>5)*KBS + (n>>4)*512 + (((c>>3)&3)*16 + (n&15))*8 + (c&7)
// so one wave's MFMA A-fragment (64 lanes x 16B) is 1KB CONTIGUOUS.

// ---------------------------------------------------------------------------
// prep1: A1t = fragment-major fp16(x), rows >=110 zeroed. Output-linear:
// thread u -> one 8-elem fragment run (16B store), reads 32B of x.
// ---------------------------------------------------------------------------
__global__ __launch_bounds__(256)
void prep1_kernel(const float* __restrict__ x, _Float16* __restrict__ A1t) {
    int u = blockIdx.x * 256 + threadIdx.x;       // 0 .. 57344
    int kb  = u / 448;                            // 448 units per kb-block
    int rem = u - kb * 448;
    int mt  = rem >> 6;
    int L   = rem & 63;
    int n   = mt * 16 + (L & 15);
    int c   = kb * 32 + (L >> 4) * 8;
    f16x8 hv;
    if (n < NN) {
        float4 v0 = *(const float4*)(x + (size_t)n * C + c);
        float4 v1 = *(const float4*)(x + (size_t)n * C + c + 4);
        hv[0]=(_Float16)v0.x; hv[1]=(_Float16)v0.y; hv[2]=(_Float16)v0.z; hv[3]=(_Float16)v0.w;
        hv[4]=(_Float16)v1.x; hv[5]=(_Float16)v1.y; hv[6]=(_Float16)v1.z; hv[7]=(_Float16)v1.w;
    } else {
        for (int e = 0; e < 8; ++e) hv[e] = (_Float16)0.f;
    }
    *(f16x8*)(A1t + (size_t)u * 8) = hv;
}

// ---------------------------------------------------------------------------
// maskprep: once-only adjacency bitmasks + degrees
// ---------------------------------------------------------------------------
__global__ __launch_bounds__(128)
void maskprep_kernel(const int* __restrict__ adj, ull* __restrict__ mlo,
                     ull* __restrict__ mhi, float* __restrict__ degs) {
    int j = threadIdx.x;
    if (j < NN) {
        ull lo = 0, hi = 0; int dg = 0;
        for (int i = 0; i < 64; ++i) {
            int m = (adj[i * NN + j] != 0);
            lo |= ((ull)m) << i; dg += m;
        }
        for (int i = 64; i < NN; ++i) {
            int m = (adj[i * NN + j] != 0);
            hi |= ((ull)m) << (i - 64); dg += m;
        }
        mlo[j] = lo; mhi[j] = hi;
        degs[j] = (float)(dg > 0 ? dg : 1);
    }
}

// ---------------------------------------------------------------------------
// mm: Cacc[0:110,:] += A(frag-major fp16) @ fp16(B fp32 row-major)
//  - A chunk (14KB, CONTIGUOUS in frag-major layout) reg-staged -> linear LDS
//  - B staged regs -> LDS (transpose+cvt), XOR-swizzled 16B granules
//  - non-draining barriers (lgkmcnt only); LOADA(it+1)/LOADB(it+2) in flight;
//    first vmem wait per iter is COMMITA's vmcnt(16) AFTER the MFMA phase.
// Block 256 thr = 4 waves, tile 112(m) x 64(n), wave w -> cols w*16..+15.
// ---------------------------------------------------------------------------
#define PIPE_BARRIER()                                                \
    do {                                                              \
        asm volatile("s_waitcnt lgkmcnt(0)" ::: "memory");            \
        __builtin_amdgcn_s_barrier();                                 \
        __builtin_amdgcn_sched_barrier(0);                            \
    } while (0)

template<int NITER>
__global__ __launch_bounds__(256, 3)
void mm_kernel(const _Float16* __restrict__ A, const float* __restrict__ B,
               float* __restrict__ Cacc) {
    __shared__ __align__(16) _Float16 As[2][2 * KBS];   // [buf][7168] linear frag order
    __shared__ __align__(16) _Float16 Bs[2][64 * 64];   // [buf][col*64 + swz k]

    const int t   = threadIdx.x;
    const int j0  = blockIdx.x * 64;
    const int kb0 = blockIdx.y * (NITER * 2);   // frag-block base (32-k units)
    const int w   = t >> 6;
    const int L   = t & 63;
    const int l15 = L & 15;
    const int q   = L >> 4;
    const int sc2 = (t & 31) * 2;     // B staging col pair
    const int kgr = (t >> 5) & 7;     // B staging k-group (8 rows)

    fx4 acc[7];
#pragma unroll
    for (int mt = 0; mt < 7; ++mt) acc[mt] = (fx4){0.f, 0.f, 0.f, 0.f};

    const float*    Bp  = B + (size_t)blockIdx.y * (NITER * 64) * C + j0 + sc2;
    const _Float16* ApC = A + (size_t)kb0 * KBS;     // chunk base (contiguous)
    const _Float16* BsR = &Bs[0][0] + (w * 16 + l15) * 64;
    const _Float16* AsR = &As[0][0];

    f16x8  av[4];          // A stage: units t, t+256, t+512, (t+768 if t<128)
    float2 bva[8], bvb[8];

#define LOADA(ch)                                                              \
    { _Pragma("unroll")                                                        \
      for (int i = 0; i < 4; ++i)                                              \
          if (i < 3 || t < 128)                                                \
              av[i] = *(const f16x8*)(ApC + (size_t)(ch) * (2 * KBS)           \
                                      + (t + i * 256) * 8); }

#define COMMITA(buf)                                                           \
    { _Pragma("unroll")                                                        \
      for (int i = 0; i < 4; ++i)                                              \
          if (i < 3 || t < 128)                                                \
              *(f16x8*)(&As[buf][0] + (t + i * 256) * 8) = av[i]; }

#define LOADB(dst, ch)                                                         \
    { _Pragma("unroll")                                                        \
      for (int p = 0; p < 8; ++p)                                              \
          dst[p] = *(const float2*)(Bp + (size_t)((ch) * 64 + kgr * 8 + p) * C); }

#define COMMITB(src, buf)                                                      \
    { f16x8 h0, h1;                                                            \
      _Pragma("unroll")                                                        \
      for (int e = 0; e < 8; ++e) { h0[e] = (_Float16)src[e].x;                \
                                    h1[e] = (_Float16)src[e].y; }              \
      *(f16x8*)(&Bs[buf][0] + sc2 * 64 + ((kgr ^ (sc2 & 7)) << 3)) = h0;       \
      *(f16x8*)(&Bs[buf][0] + (sc2 + 1) * 64 + ((kgr ^ ((sc2 + 1) & 7)) << 3)) = h1; }

    // prologue: chunk0 -> LDS (one-time deep vmcnt stall); chunk1 B -> regs
    LOADA(0);
    LOADB(bva, 0);
    COMMITA(0);
    COMMITB(bva, 0);
    LOADB(bva, 1);
    PIPE_BARRIER();

#pragma unroll
    for (int it = 0; it < NITER; ++it) {
        if (it + 1 < NITER) LOADA(it + 1);          // oldest vmem this iter
        __builtin_amdgcn_sched_barrier(0);
        if (it + 2 < NITER) {                       // newest; stays in flight
            if (it & 1) { LOADB(bva, it + 2); } else { LOADB(bvb, it + 2); }
        }
        __builtin_amdgcn_sched_barrier(0);
        // MFMA phase: LDS-only reads (lgkm waits), no vmem wait here
#pragma unroll
        for (int s = 0; s < 2; ++s) {
            f16x8 bf = *(const f16x8*)(BsR + (it & 1) * 4096
                            + ((((s << 2) + q) ^ (l15 & 7)) << 3));
#pragma unroll
            for (int mt = 0; mt < 7; ++mt) {
                f16x8 afrag = *(const f16x8*)(AsR + (it & 1) * (2 * KBS)
                                  + (s * 7 + mt) * 512 + L * 8);
                acc[mt] = __builtin_amdgcn_mfma_f32_16x16x32_f16(
                    afrag, bf, acc[mt], 0, 0, 0);
            }
        }
        // commits: av wait retires to vmcnt(16) (B it+2 still outstanding);
        // bvb/bva regs loaded a full iter ago -> already retired.
        if (it + 1 < NITER) {
            COMMITA((it + 1) & 1);
            if (it & 1) { COMMITB(bvb, (it + 1) & 1); }
            else        { COMMITB(bva, (it + 1) & 1); }
            PIPE_BARRIER();
            // hazard: COMMIT writes buf[(it+1)&1]; last reader was iter it-1's
            // MFMA, separated by iter it-1's barrier. lgkmcnt(0)+s_barrier
            // publishes; sched_barrier(0) pins next iter's ds_reads below.
        }
    }

    // epilogue: fp32 atomic accumulate (C/D: col=lane&15, row=q*4+reg)
    const int col = j0 + w * 16 + l15;
#pragma unroll
    for (int mt = 0; mt < 7; ++mt)
#pragma unroll
        for (int r = 0; r < 4; ++r) {
            int row = mt * 16 + q * 4 + r;
            if (row < NN)
                atomicAdd(&Cacc[(size_t)row * C + col], acc[mt][r]);
        }
#undef LOADA
#undef COMMITA
#undef LOADB
#undef COMMITB
}

// ---------------------------------------------------------------------------
// agg: per 16-col tile, builds A3t = frag-major fp16([h+b2, aggr]) [112][8192]
// ---------------------------------------------------------------------------
__device__ __forceinline__ size_t fragidx(int n, int c) {
    return (size_t)(c >> 5) * KBS + (n >> 4) * 512
         + (((c >> 3) & 3) * 16 + (n & 15)) * 8 + (c & 7);
}

__global__ __launch_bounds__(256)
void agg_kernel(const float* __restrict__ h_raw, const ull* __restrict__ gmlo,
                const ull* __restrict__ gmhi, const float* __restrict__ gdegs,
                const float* __restrict__ b2, _Float16* __restrict__ A3t) {
    __shared__ float hb[NN * 16];
    const int t  = threadIdx.x;
    const int c0 = blockIdx.x * 16;

    for (int idx = t; idx < NN * 8; idx += 256) {
        int n = idx >> 3, cp = (idx & 7) << 1;
        float2 v = *(const float2*)(h_raw + (size_t)n * C + c0 + cp);
        float v0 = v.x + b2[c0 + cp];
        float v1 = v.y + b2[c0 + cp + 1];
        hb[n * 16 + cp]     = v0;
        hb[n * 16 + cp + 1] = v1;
        union { _Float16 h[2]; unsigned u; } pk;
        pk.h[0] = (_Float16)v0;
        pk.h[1] = (_Float16)v1;
        *(unsigned*)(A3t + fragidx(n, c0 + cp)) = pk.u;
    }
    // zero pad rows 110,111 for both halves of this c-tile
    if (t < 32) {
        int n  = 110 + ((t >> 3) & 1);
        int hs = t >> 4;
        int cp = (t & 7) << 1;
        *(unsigned*)(A3t + fragidx(n, hs * C + c0 + cp)) = 0u;
    }
    __syncthreads();
    for (int idx = t; idx < NN * 8; idx += 256) {
        int j = idx >> 3, cp = (idx & 7) << 1;
        ull lo = gmlo[j], hi = gmhi[j];
        float dg = gdegs[j];
        float a0 = 0.f, a1 = 0.f;
        for (int i = 0; i < 64; ++i)
            if ((lo >> i) & 1) { a0 += hb[i * 16 + cp]; a1 += hb[i * 16 + cp + 1]; }
        for (int i = 64; i < NN; ++i)
            if ((hi >> (i - 64)) & 1) { a0 += hb[i * 16 + cp]; a1 += hb[i * 16 + cp + 1]; }
        union { _Float16 h[2]; unsigned u; } pk;
        pk.h[0] = (_Float16)(a0 / dg);
        pk.h[1] = (_Float16)(a1 / dg);
        *(unsigned*)(A3t + fragidx(j, C + c0 + cp)) = pk.u;
    }
}

// ---------------------------------------------------------------------------
// fin: out[j,c] = sum_k Wl[j,k] * relu(z_raw[k,c]+b1[c]) + bl[j]
// ---------------------------------------------------------------------------
__global__ __launch_bounds__(256)
void fin_kernel(const float* __restrict__ z_raw, const float* __restrict__ b1,
                const float* __restrict__ Wl, const float* __restrict__ bl,
                float* __restrict__ out) {
    __shared__ float zs[NN * 64];
    const int t  = threadIdx.x;
    const int c0 = blockIdx.x * 64;
    const int c  = t & 63;

    for (int idx = t; idx < NN * 64; idx += 256) {
        int k = idx >> 6, cc = idx & 63;
        float v = z_raw[(size_t)k * C + c0 + cc] + b1[c0 + cc];
        zs[idx] = fmaxf(v, 0.f);
    }
    __syncthreads();
    for (int jj = 0; jj < 7; ++jj) {
        int j = blockIdx.y * 28 + jj * 4 + (t >> 6);
        if (j < NN) {
            float a = bl[j];
#pragma unroll 2
            for (int k = 0; k < NN; ++k)
                a += Wl[j * NN + k] * zs[k * 64 + c];   // Wl wave-uniform -> scalar
            out[(size_t)j * C + c0 + c] = a;
        }
    }
}

// ---------------------------------------------------------------------------
extern "C" void kernel_launch(void* const* d_in, const int* in_sizes, int n_in,
                              void* d_out, int out_size, void* d_ws, size_t ws_size,
                              hipStream_t stream) {
    const float* x   = (const float*)d_in[0];
    const int*   adj = (const int*)d_in[1];
    const float* W2  = (const float*)d_in[2];
    const float* b2  = (const float*)d_in[3];
    const float* W1  = (const float*)d_in[4];
    const float* b1  = (const float*)d_in[5];
    const float* Wl  = (const float*)d_in[6];
    const float* bl  = (const float*)d_in[7];
    float* out = (float*)d_out;

    char* ws = (char*)d_ws;
    float*    h_raw = (float*)(ws);                    // 110*4096 f32
    float*    z_raw = (float*)(ws + 1802240);          // 110*4096 f32
    _Float16* A1t   = (_Float16*)(ws + 3604480);       // 112*4096 f16 frag-major
    _Float16* A3t   = (_Float16*)(ws + 4521984);       // 112*8192 f16 frag-major
    ull*      mlo   = (ull*)(ws + 6356992);            // 110 u64
    ull*      mhi   = (ull*)(ws + 6357872);            // 110 u64
    float*    degs  = (float*)(ws + 6358752);          // 110 f32

    hipMemsetAsync(d_ws, 0, 3604480, stream);                        // zero h_raw,z_raw
    prep1_kernel<<<224, 256, 0, stream>>>(x, A1t);                   // 57344 units
    maskprep_kernel<<<1, 128, 0, stream>>>(adj, mlo, mhi, degs);
    mm_kernel<4><<<dim3(64, 16), 256, 0, stream>>>(A1t, W2, h_raw);
    agg_kernel<<<C / 16, 256, 0, stream>>>(h_raw, mlo, mhi, degs, b2, A3t);
    mm_kernel<8><<<dim3(64, 16), 256, 0, stream>>>(A3t, W1, z_raw);
    fin_kernel<<<dim3(C / 64, 4), 256, 0, stream>>>(z_raw, b1, Wl, bl, out);
}

// Round 6
// 352.091 us; speedup vs baseline: 1.1143x; 1.0096x over previous
//
#include <hip/hip_runtime.h>
#include <hip/hip_fp16.h>

#define C 4096
#define NN 110
#define MPAD 112
#define NMT 7                // m-tiles of 16 (112 rows)
#define KBS (NMT * 512)      // halves per 32-k fragment block = 3584
#define NSLICE 8             // K-split slices per GEMM

typedef _Float16 f16x8 __attribute__((ext_vector_type(8)));
typedef float fx4 __attribute__((ext_vector_type(4)));
typedef unsigned long long ull;

// Fragment-major layout for fp16 A operands:
//   idx(n,c) = (c>>5)*KBS + (n>>4)*512 + (((c>>3)&3)*16 + (n&15))*8 + (c&7)
// so one wave's MFMA A-fragment (64 lanes x 16B) is 1KB CONTIGUOUS.

// ---------------------------------------------------------------------------
// prep1: A1t = fragment-major fp16(x), rows >=110 zeroed.
// ---------------------------------------------------------------------------
__global__ __launch_bounds__(256)
void prep1_kernel(const float* __restrict__ x, _Float16* __restrict__ A1t) {
    int u = blockIdx.x * 256 + threadIdx.x;       // 0 .. 57343
    int kb  = u / 448;
    int rem = u - kb * 448;
    int mt  = rem >> 6;
    int L   = rem & 63;
    int n   = mt * 16 + (L & 15);
    int c   = kb * 32 + (L >> 4) * 8;
    f16x8 hv;
    if (n < NN) {
        float4 v0 = *(const float4*)(x + (size_t)n * C + c);
        float4 v1 = *(const float4*)(x + (size_t)n * C + c + 4);
        hv[0]=(_Float16)v0.x; hv[1]=(_Float16)v0.y; hv[2]=(_Float16)v0.z; hv[3]=(_Float16)v0.w;
        hv[4]=(_Float16)v1.x; hv[5]=(_Float16)v1.y; hv[6]=(_Float16)v1.z; hv[7]=(_Float16)v1.w;
    } else {
        for (int e = 0; e < 8; ++e) hv[e] = (_Float16)0.f;
    }
    *(f16x8*)(A1t + (size_t)u * 8) = hv;
}

// ---------------------------------------------------------------------------
// maskprep: once-only adjacency bitmasks + degrees
// ---------------------------------------------------------------------------
__global__ __launch_bounds__(128)
void maskprep_kernel(const int* __restrict__ adj, ull* __restrict__ mlo,
                     ull* __restrict__ mhi, float* __restrict__ degs) {
    int j = threadIdx.x;
    if (j < NN) {
        ull lo = 0, hi = 0; int dg = 0;
        for (int i = 0; i < 64; ++i) {
            int m = (adj[i * NN + j] != 0);
            lo |= ((ull)m) << i; dg += m;
        }
        for (int i = 64; i < NN; ++i) {
            int m = (adj[i * NN + j] != 0);
            hi |= ((ull)m) << (i - 64); dg += m;
        }
        mlo[j] = lo; mhi[j] = hi;
        degs[j] = (float)(dg > 0 ? dg : 1);
    }
}

// ---------------------------------------------------------------------------
// mm: part[y] = A(frag-major fp16, k-slice y) @ fp16(B fp32 row-major slice)
//  - A chunk (14KB contiguous) reg-staged -> linear LDS
//  - B staged regs -> LDS (transpose+cvt), XOR-swizzled 16B granules
//  - non-draining barriers (lgkmcnt only); LOADA(it+1)/LOADB(it+2) in flight
//  - NO atomics: plain stores of the 112x64 partial tile into slice y.
// Block 256 thr = 4 waves, tile 112(m) x 64(n); grid (64, NSLICE) = 512
// blocks -> single residency round at 3 blocks/CU (no tail).
// ---------------------------------------------------------------------------
#define PIPE_BARRIER()                                                \
    do {                                                              \
        asm volatile("s_waitcnt lgkmcnt(0)" ::: "memory");            \
        __builtin_amdgcn_s_barrier();                                 \
        __builtin_amdgcn_sched_barrier(0);                            \
    } while (0)

template<int NITER>
__global__ __launch_bounds__(256, 3)
void mm_kernel(const _Float16* __restrict__ A, const float* __restrict__ B,
               float* __restrict__ Cpart) {
    __shared__ __align__(16) _Float16 As[2][2 * KBS];   // [buf][7168] linear frag order
    __shared__ __align__(16) _Float16 Bs[2][64 * 64];   // [buf][col*64 + swz k]

    const int t   = threadIdx.x;
    const int j0  = blockIdx.x * 64;
    const int w   = t >> 6;
    const int L   = t & 63;
    const int l15 = L & 15;
    const int q   = L >> 4;
    const int sc2 = (t & 31) * 2;     // B staging col pair
    const int kgr = (t >> 5) & 7;     // B staging k-group (8 rows)

    fx4 acc[7];
#pragma unroll
    for (int mt = 0; mt < 7; ++mt) acc[mt] = (fx4){0.f, 0.f, 0.f, 0.f};

    const float*    Bp  = B + (size_t)blockIdx.y * (NITER * 64) * C + j0 + sc2;
    const _Float16* ApC = A + (size_t)blockIdx.y * (NITER * 2) * KBS;
    const _Float16* BsR = &Bs[0][0] + (w * 16 + l15) * 64;
    const _Float16* AsR = &As[0][0];

    f16x8  av[4];          // A stage: units t, t+256, t+512, (t+768 if t<128)
    float2 bva[8], bvb[8];

#define LOADA(ch)                                                              \
    { _Pragma("unroll")                                                        \
      for (int i = 0; i < 4; ++i)                                              \
          if (i < 3 || t < 128)                                                \
              av[i] = *(const f16x8*)(ApC + (size_t)(ch) * (2 * KBS)           \
                                      + (t + i * 256) * 8); }

#define COMMITA(buf)                                                           \
    { _Pragma("unroll")                                                        \
      for (int i = 0; i < 4; ++i)                                              \
          if (i < 3 || t < 128)                                                \
              *(f16x8*)(&As[buf][0] + (t + i * 256) * 8) = av[i]; }

#define LOADB(dst, ch)                                                         \
    { _Pragma("unroll")                                                        \
      for (int p = 0; p < 8; ++p)                                              \
          dst[p] = *(const float2*)(Bp + (size_t)((ch) * 64 + kgr * 8 + p) * C); }

#define COMMITB(src, buf)                                                      \
    { f16x8 h0, h1;                                                            \
      _Pragma("unroll")                                                        \
      for (int e = 0; e < 8; ++e) { h0[e] = (_Float16)src[e].x;                \
                                    h1[e] = (_Float16)src[e].y; }              \
      *(f16x8*)(&Bs[buf][0] + sc2 * 64 + ((kgr ^ (sc2 & 7)) << 3)) = h0;       \
      *(f16x8*)(&Bs[buf][0] + (sc2 + 1) * 64 + ((kgr ^ ((sc2 + 1) & 7)) << 3)) = h1; }

    // prologue: chunk0 -> LDS (one-time deep vmcnt stall); chunk1 B -> regs
    LOADA(0);
    LOADB(bva, 0);
    COMMITA(0);
    COMMITB(bva, 0);
    LOADB(bva, 1);
    PIPE_BARRIER();

#pragma unroll
    for (int it = 0; it < NITER; ++it) {
        if (it + 1 < NITER) LOADA(it + 1);          // oldest vmem this iter
        __builtin_amdgcn_sched_barrier(0);
        if (it + 2 < NITER) {                       // newest; stays in flight
            if (it & 1) { LOADB(bva, it + 2); } else { LOADB(bvb, it + 2); }
        }
        __builtin_amdgcn_sched_barrier(0);
        // MFMA phase: LDS-only reads (lgkm waits), no vmem wait here
#pragma unroll
        for (int s = 0; s < 2; ++s) {
            f16x8 bf = *(const f16x8*)(BsR + (it & 1) * 4096
                            + ((((s << 2) + q) ^ (l15 & 7)) << 3));
#pragma unroll
            for (int mt = 0; mt < 7; ++mt) {
                f16x8 afrag = *(const f16x8*)(AsR + (it & 1) * (2 * KBS)
                                  + (s * 7 + mt) * 512 + L * 8);
                acc[mt] = __builtin_amdgcn_mfma_f32_16x16x32_f16(
                    afrag, bf, acc[mt], 0, 0, 0);
            }
        }
        // commits: av wait retires to vmcnt(16) (B it+2 still outstanding)
        if (it + 1 < NITER) {
            COMMITA((it + 1) & 1);
            if (it & 1) { COMMITB(bvb, (it + 1) & 1); }
            else        { COMMITB(bva, (it + 1) & 1); }
            PIPE_BARRIER();
            // hazard: COMMIT writes buf[(it+1)&1]; last reader was iter it-1's
            // MFMA, separated by iter it-1's barrier.
        }
    }

    // epilogue: plain coalesced stores of this K-slice's partial tile
    float* Cp = Cpart + (size_t)blockIdx.y * (NN * C) + j0 + w * 16 + l15;
#pragma unroll
    for (int mt = 0; mt < 7; ++mt)
#pragma unroll
        for (int r = 0; r < 4; ++r) {
            int row = mt * 16 + q * 4 + r;
            if (row < NN)
                Cp[(size_t)row * C] = acc[mt][r];
        }
#undef LOADA
#undef COMMITA
#undef LOADB
#undef COMMITB
}

// ---------------------------------------------------------------------------
// agg: per 16-col tile; reduces the 8 h-partials (+b2) in-flight, builds
// A3t = frag-major fp16([h, aggr]) [112][8192]
// ---------------------------------------------------------------------------
__device__ __forceinline__ size_t fragidx(int n, int c) {
    return (size_t)(c >> 5) * KBS + (n >> 4) * 512
         + (((c >> 3) & 3) * 16 + (n & 15)) * 8 + (c & 7);
}

__global__ __launch_bounds__(256)
void agg_kernel(const float* __restrict__ hpart, const ull* __restrict__ gmlo,
                const ull* __restrict__ gmhi, const float* __restrict__ gdegs,
                const float* __restrict__ b2, _Float16* __restrict__ A3t) {
    __shared__ float hb[NN * 16];
    const int t  = threadIdx.x;
    const int c0 = blockIdx.x * 16;

    for (int idx = t; idx < NN * 8; idx += 256) {
        int n = idx >> 3, cp = (idx & 7) << 1;
        float v0 = b2[c0 + cp], v1 = b2[c0 + cp + 1];
#pragma unroll
        for (int p = 0; p < NSLICE; ++p) {
            float2 v = *(const float2*)(hpart + (size_t)p * (NN * C)
                                        + (size_t)n * C + c0 + cp);
            v0 += v.x; v1 += v.y;
        }
        hb[n * 16 + cp]     = v0;
        hb[n * 16 + cp + 1] = v1;
        union { _Float16 h[2]; unsigned u; } pk;
        pk.h[0] = (_Float16)v0;
        pk.h[1] = (_Float16)v1;
        *(unsigned*)(A3t + fragidx(n, c0 + cp)) = pk.u;
    }
    // zero pad rows 110,111 for both halves of this c-tile
    if (t < 32) {
        int n  = 110 + ((t >> 3) & 1);
        int hs = t >> 4;
        int cp = (t & 7) << 1;
        *(unsigned*)(A3t + fragidx(n, hs * C + c0 + cp)) = 0u;
    }
    __syncthreads();
    for (int idx = t; idx < NN * 8; idx += 256) {
        int j = idx >> 3, cp = (idx & 7) << 1;
        ull lo = gmlo[j], hi = gmhi[j];
        float dg = gdegs[j];
        float a0 = 0.f, a1 = 0.f;
        for (int i = 0; i < 64; ++i)
            if ((lo >> i) & 1) { a0 += hb[i * 16 + cp]; a1 += hb[i * 16 + cp + 1]; }
        for (int i = 64; i < NN; ++i)
            if ((hi >> (i - 64)) & 1) { a0 += hb[i * 16 + cp]; a1 += hb[i * 16 + cp + 1]; }
        union { _Float16 h[2]; unsigned u; } pk;
        pk.h[0] = (_Float16)(a0 / dg);
        pk.h[1] = (_Float16)(a1 / dg);
        *(unsigned*)(A3t + fragidx(j, C + c0 + cp)) = pk.u;
    }
}

// ---------------------------------------------------------------------------
// zred: z_raw = sum of 8 z-partials (float4 streaming)
// ---------------------------------------------------------------------------
__global__ __launch_bounds__(256)
void zred_kernel(const float* __restrict__ zpart, float* __restrict__ z_raw) {
    int idx = blockIdx.x * 256 + threadIdx.x;     // float4 units: 110*1024
    if (idx < NN * (C / 4)) {
        fx4 s = (fx4){0.f, 0.f, 0.f, 0.f};
#pragma unroll
        for (int p = 0; p < NSLICE; ++p) {
            fx4 v = *(const fx4*)(zpart + (size_t)p * (NN * C) + (size_t)idx * 4);
            s.x += v.x; s.y += v.y; s.z += v.z; s.w += v.w;
        }
        *(fx4*)(z_raw + (size_t)idx * 4) = s;
    }
}

// ---------------------------------------------------------------------------
// fin: out[j,c] = sum_k Wl[j,k] * relu(z_raw[k,c]+b1[c]) + bl[j]
// ---------------------------------------------------------------------------
__global__ __launch_bounds__(256)
void fin_kernel(const float* __restrict__ z_raw, const float* __restrict__ b1,
                const float* __restrict__ Wl, const float* __restrict__ bl,
                float* __restrict__ out) {
    __shared__ float zs[NN * 64];
    const int t  = threadIdx.x;
    const int c0 = blockIdx.x * 64;
    const int c  = t & 63;

    for (int idx = t; idx < NN * 64; idx += 256) {
        int k = idx >> 6, cc = idx & 63;
        float v = z_raw[(size_t)k * C + c0 + cc] + b1[c0 + cc];
        zs[idx] = fmaxf(v, 0.f);
    }
    __syncthreads();
    for (int jj = 0; jj < 7; ++jj) {
        int j = blockIdx.y * 28 + jj * 4 + (t >> 6);
        if (j < NN) {
            float a = bl[j];
#pragma unroll 2
            for (int k = 0; k < NN; ++k)
                a += Wl[j * NN + k] * zs[k * 64 + c];   // Wl wave-uniform -> scalar
            out[(size_t)j * C + c0 + c] = a;
        }
    }
}

// ---------------------------------------------------------------------------
extern "C" void kernel_launch(void* const* d_in, const int* in_sizes, int n_in,
                              void* d_out, int out_size, void* d_ws, size_t ws_size,
                              hipStream_t stream) {
    const float* x   = (const float*)d_in[0];
    const int*   adj = (const int*)d_in[1];
    const float* W2  = (const float*)d_in[2];
    const float* b2  = (const float*)d_in[3];
    const float* W1  = (const float*)d_in[4];
    const float* b1  = (const float*)d_in[5];
    const float* Wl  = (const float*)d_in[6];
    const float* bl  = (const float*)d_in[7];
    float* out = (float*)d_out;

    char* ws = (char*)d_ws;
    float*    hpart = (float*)(ws);                    // 8 x 110*4096 f32 = 14417920 B
    float*    zpart = (float*)(ws + 14417920);         // 8 x 110*4096 f32 = 14417920 B
    float*    z_raw = (float*)(ws + 28835840);         // 110*4096 f32    = 1802240 B
    _Float16* A1t   = (_Float16*)(ws + 30638080);      // 112*4096 f16 frag-major
    _Float16* A3t   = (_Float16*)(ws + 31555584);      // 112*8192 f16 frag-major
    ull*      mlo   = (ull*)(ws + 33390592);           // 110 u64
    ull*      mhi   = (ull*)(ws + 33391472);           // 110 u64
    float*    degs  = (float*)(ws + 33392352);         // 110 f32

    // no memset needed: all buffers fully overwritten each call
    prep1_kernel<<<224, 256, 0, stream>>>(x, A1t);
    maskprep_kernel<<<1, 128, 0, stream>>>(adj, mlo, mhi, degs);
    mm_kernel<8><<<dim3(64, NSLICE), 256, 0, stream>>>(A1t, W2, hpart);
    agg_kernel<<<C / 16, 256, 0, stream>>>(hpart, mlo, mhi, degs, b2, A3t);
    mm_kernel<16><<<dim3(64, NSLICE), 256, 0, stream>>>(A3t, W1, zpart);
    zred_kernel<<<440, 256, 0, stream>>>(zpart, z_raw);
    fin_kernel<<<dim3(C / 64, 4), 256, 0, stream>>>(z_raw, b1, Wl, bl, out);
}

// Round 7
// 347.841 us; speedup vs baseline: 1.1279x; 1.0122x over previous
//
#include <hip/hip_runtime.h>
#include <hip/hip_fp16.h>

#define C 4096
#define NN 110
#define MPAD 112
#define NMT 7                // m-tiles of 16 (112 rows)
#define KBS (NMT * 512)      // halves per 32-k fragment block = 3584
#define NSLICE 8             // K-split slices per GEMM

typedef _Float16 f16x8 __attribute__((ext_vector_type(8)));
typedef float fx4 __attribute__((ext_vector_type(4)));
typedef unsigned long long ull;

// Fragment-major layout for fp16 A operands:
//   idx(n,c) = (c>>5)*KBS + (n>>4)*512 + (((c>>3)&3)*16 + (n&15))*8 + (c&7)
// so one wave's MFMA A-fragment (64 lanes x 16B) is 1KB CONTIGUOUS.

// ---------------------------------------------------------------------------
// prep1: A1t = fragment-major fp16(x), rows >=110 zeroed.
// block 224 additionally builds adjacency bitmasks + degrees (merged maskprep).
// ---------------------------------------------------------------------------
__global__ __launch_bounds__(256)
void prep1_kernel(const float* __restrict__ x, _Float16* __restrict__ A1t,
                  const int* __restrict__ adj, ull* __restrict__ mlo,
                  ull* __restrict__ mhi, float* __restrict__ degs) {
    if (blockIdx.x == 224) {                      // maskprep block
        int j = threadIdx.x;
        if (j < NN) {
            ull lo = 0, hi = 0; int dg = 0;
            for (int i = 0; i < 64; ++i) {
                int m = (adj[i * NN + j] != 0);
                lo |= ((ull)m) << i; dg += m;
            }
            for (int i = 64; i < NN; ++i) {
                int m = (adj[i * NN + j] != 0);
                hi |= ((ull)m) << (i - 64); dg += m;
            }
            mlo[j] = lo; mhi[j] = hi;
            degs[j] = (float)(dg > 0 ? dg : 1);
        }
        return;
    }
    int u = blockIdx.x * 256 + threadIdx.x;       // 0 .. 57343
    int kb  = u / 448;
    int rem = u - kb * 448;
    int mt  = rem >> 6;
    int L   = rem & 63;
    int n   = mt * 16 + (L & 15);
    int c   = kb * 32 + (L >> 4) * 8;
    f16x8 hv;
    if (n < NN) {
        float4 v0 = *(const float4*)(x + (size_t)n * C + c);
        float4 v1 = *(const float4*)(x + (size_t)n * C + c + 4);
        hv[0]=(_Float16)v0.x; hv[1]=(_Float16)v0.y; hv[2]=(_Float16)v0.z; hv[3]=(_Float16)v0.w;
        hv[4]=(_Float16)v1.x; hv[5]=(_Float16)v1.y; hv[6]=(_Float16)v1.z; hv[7]=(_Float16)v1.w;
    } else {
        for (int e = 0; e < 8; ++e) hv[e] = (_Float16)0.f;
    }
    *(f16x8*)(A1t + (size_t)u * 8) = hv;
}

// ---------------------------------------------------------------------------
// mm: part[y] = A(frag-major fp16, k-slice y) @ fp16(B fp32 row-major slice)
//  - A-fragments loaded DIRECT global(L2) -> VGPR, reg-double-buffered.
//    NO A LDS round-trip (frag = 1KB contiguous; A is L2-resident ~200cyc,
//    hidden by one full iteration). DS traffic/blk-iter: 86KB -> 16KB.
//  - B staged regs -> LDS dbuf (transpose+cvt), XOR-swizzled 16B granules,
//    loads issued 2 iters ahead, non-draining barriers (lgkmcnt only).
// Block 256 thr = 4 waves, tile 112(m) x 64(n); grid (64, NSLICE) = 512
// blocks = one residency round at 2 blocks/CU.
// ---------------------------------------------------------------------------
#define PIPE_BARRIER()                                                \
    do {                                                              \
        asm volatile("s_waitcnt lgkmcnt(0)" ::: "memory");            \
        __builtin_amdgcn_s_barrier();                                 \
        __builtin_amdgcn_sched_barrier(0);                            \
    } while (0)

template<int NITER>
__global__ __launch_bounds__(256, 2)
void mm_kernel(const _Float16* __restrict__ A, const float* __restrict__ B,
               float* __restrict__ Cpart) {
    __shared__ __align__(16) _Float16 Bs[2][64 * 64];   // [buf][col*64 + swz k]

    const int t   = threadIdx.x;
    const int j0  = blockIdx.x * 64;
    const int w   = t >> 6;
    const int L   = t & 63;
    const int l15 = L & 15;
    const int q   = L >> 4;
    const int sc2 = (t & 31) * 2;     // B staging col pair
    const int kgr = (t >> 5) & 7;     // B staging k-group (8 rows)

    fx4 acc[7];
#pragma unroll
    for (int mt = 0; mt < 7; ++mt) acc[mt] = (fx4){0.f, 0.f, 0.f, 0.f};

    const float*    Bp  = B + (size_t)blockIdx.y * (NITER * 64) * C + j0 + sc2;
    const _Float16* ApL = A + (size_t)blockIdx.y * (NITER * 2) * KBS + L * 8;
    const _Float16* BsR = &Bs[0][0] + (w * 16 + l15) * 64;

    f16x8  af[2][2][7];    // [regbuf][s][mt] — all indices compile-time after unroll
    float2 bva[8], bvb[8];

#define LOADAF(buf, ch)                                                        \
    { _Pragma("unroll")                                                        \
      for (int s = 0; s < 2; ++s)                                              \
          _Pragma("unroll")                                                    \
          for (int mt = 0; mt < 7; ++mt)                                       \
              af[buf][s][mt] = *(const f16x8*)(ApL                             \
                  + (size_t)((ch) * 2 + s) * KBS + mt * 512); }

#define LOADB(dst, ch)                                                         \
    { _Pragma("unroll")                                                        \
      for (int p = 0; p < 8; ++p)                                              \
          dst[p] = *(const float2*)(Bp + (size_t)((ch) * 64 + kgr * 8 + p) * C); }

#define COMMITB(src, buf)                                                      \
    { f16x8 h0, h1;                                                            \
      _Pragma("unroll")                                                        \
      for (int e = 0; e < 8; ++e) { h0[e] = (_Float16)src[e].x;                \
                                    h1[e] = (_Float16)src[e].y; }              \
      *(f16x8*)(&Bs[buf][0] + sc2 * 64 + ((kgr ^ (sc2 & 7)) << 3)) = h0;       \
      *(f16x8*)(&Bs[buf][0] + (sc2 + 1) * 64 + ((kgr ^ ((sc2 + 1) & 7)) << 3)) = h1; }

    // prologue: A(0) -> regs, B(0) -> LDS (one-time stall), B(1) -> regs
    LOADAF(0, 0);
    LOADB(bva, 0);
    COMMITB(bva, 0);
    LOADB(bva, 1);
    PIPE_BARRIER();

#pragma unroll
    for (int it = 0; it < NITER; ++it) {
        if (it + 1 < NITER) LOADAF((it + 1) & 1, it + 1);   // L2 hit ~200cyc, used next iter
        __builtin_amdgcn_sched_barrier(0);
        if (it + 2 < NITER) {                               // newest; in flight across barrier
            if (it & 1) { LOADB(bva, it + 2); } else { LOADB(bvb, it + 2); }
        }
        __builtin_amdgcn_sched_barrier(0);
        // MFMA phase: af[it&1] regs (vmcnt wait leaves 22 newer loads live)
        // + B fragment from LDS (lgkm wait)
#pragma unroll
        for (int s = 0; s < 2; ++s) {
            f16x8 bf = *(const f16x8*)(BsR + (it & 1) * 4096
                            + ((((s << 2) + q) ^ (l15 & 7)) << 3));
#pragma unroll
            for (int mt = 0; mt < 7; ++mt)
                acc[mt] = __builtin_amdgcn_mfma_f32_16x16x32_f16(
                    af[it & 1][s][mt], bf, acc[mt], 0, 0, 0);
        }
        // commit B(it+1): its regs retired by the MFMA-phase vmcnt already
        if (it + 1 < NITER) {
            if (it & 1) { COMMITB(bvb, (it + 1) & 1); }
            else        { COMMITB(bva, (it + 1) & 1); }
            PIPE_BARRIER();
            // hazard: COMMITB writes buf[(it+1)&1]; last reader was iter it-1's
            // MFMA, separated by iter it-1's barrier.
        }
    }

    // epilogue: plain coalesced stores of this K-slice's partial tile
    float* Cp = Cpart + (size_t)blockIdx.y * (NN * C) + j0 + w * 16 + l15;
#pragma unroll
    for (int mt = 0; mt < 7; ++mt)
#pragma unroll
        for (int r = 0; r < 4; ++r) {
            int row = mt * 16 + q * 4 + r;
            if (row < NN)
                Cp[(size_t)row * C] = acc[mt][r];
        }
#undef LOADAF
#undef LOADB
#undef COMMITB
}

// ---------------------------------------------------------------------------
// agg: per 16-col tile; reduces the 8 h-partials (+b2) in-flight, builds
// A3t = frag-major fp16([h, aggr]) [112][8192]
// ---------------------------------------------------------------------------
__device__ __forceinline__ size_t fragidx(int n, int c) {
    return (size_t)(c >> 5) * KBS + (n >> 4) * 512
         + (((c >> 3) & 3) * 16 + (n & 15)) * 8 + (c & 7);
}

__global__ __launch_bounds__(256)
void agg_kernel(const float* __restrict__ hpart, const ull* __restrict__ gmlo,
                const ull* __restrict__ gmhi, const float* __restrict__ gdegs,
                const float* __restrict__ b2, _Float16* __restrict__ A3t) {
    __shared__ float hb[NN * 16];
    const int t  = threadIdx.x;
    const int c0 = blockIdx.x * 16;

    for (int idx = t; idx < NN * 8; idx += 256) {
        int n = idx >> 3, cp = (idx & 7) << 1;
        float v0 = b2[c0 + cp], v1 = b2[c0 + cp + 1];
#pragma unroll
        for (int p = 0; p < NSLICE; ++p) {
            float2 v = *(const float2*)(hpart + (size_t)p * (NN * C)
                                        + (size_t)n * C + c0 + cp);
            v0 += v.x; v1 += v.y;
        }
        hb[n * 16 + cp]     = v0;
        hb[n * 16 + cp + 1] = v1;
        union { _Float16 h[2]; unsigned u; } pk;
        pk.h[0] = (_Float16)v0;
        pk.h[1] = (_Float16)v1;
        *(unsigned*)(A3t + fragidx(n, c0 + cp)) = pk.u;
    }
    // zero pad rows 110,111 for both halves of this c-tile
    if (t < 32) {
        int n  = 110 + ((t >> 3) & 1);
        int hs = t >> 4;
        int cp = (t & 7) << 1;
        *(unsigned*)(A3t + fragidx(n, hs * C + c0 + cp)) = 0u;
    }
    __syncthreads();
    for (int idx = t; idx < NN * 8; idx += 256) {
        int j = idx >> 3, cp = (idx & 7) << 1;
        ull lo = gmlo[j], hi = gmhi[j];
        float dg = gdegs[j];
        float a0 = 0.f, a1 = 0.f;
        for (int i = 0; i < 64; ++i)
            if ((lo >> i) & 1) { a0 += hb[i * 16 + cp]; a1 += hb[i * 16 + cp + 1]; }
        for (int i = 64; i < NN; ++i)
            if ((hi >> (i - 64)) & 1) { a0 += hb[i * 16 + cp]; a1 += hb[i * 16 + cp + 1]; }
        union { _Float16 h[2]; unsigned u; } pk;
        pk.h[0] = (_Float16)(a0 / dg);
        pk.h[1] = (_Float16)(a1 / dg);
        *(unsigned*)(A3t + fragidx(j, C + c0 + cp)) = pk.u;
    }
}

// ---------------------------------------------------------------------------
// zred: z_raw = sum of 8 z-partials (float4 streaming)
// ---------------------------------------------------------------------------
__global__ __launch_bounds__(256)
void zred_kernel(const float* __restrict__ zpart, float* __restrict__ z_raw) {
    int idx = blockIdx.x * 256 + threadIdx.x;     // float4 units: 110*1024
    if (idx < NN * (C / 4)) {
        fx4 s = (fx4){0.f, 0.f, 0.f, 0.f};
#pragma unroll
        for (int p = 0; p < NSLICE; ++p) {
            fx4 v = *(const fx4*)(zpart + (size_t)p * (NN * C) + (size_t)idx * 4);
            s.x += v.x; s.y += v.y; s.z += v.z; s.w += v.w;
        }
        *(fx4*)(z_raw + (size_t)idx * 4) = s;
    }
}

// ---------------------------------------------------------------------------
// fin: out[j,c] = sum_k Wl[j,k] * relu(z_raw[k,c]+b1[c]) + bl[j]
// ---------------------------------------------------------------------------
__global__ __launch_bounds__(256)
void fin_kernel(const float* __restrict__ z_raw, const float* __restrict__ b1,
                const float* __restrict__ Wl, const float* __restrict__ bl,
                float* __restrict__ out) {
    __shared__ float zs[NN * 64];
    const int t  = threadIdx.x;
    const int c0 = blockIdx.x * 64;
    const int c  = t & 63;

    for (int idx = t; idx < NN * 64; idx += 256) {
        int k = idx >> 6, cc = idx & 63;
        float v = z_raw[(size_t)k * C + c0 + cc] + b1[c0 + cc];
        zs[idx] = fmaxf(v, 0.f);
    }
    __syncthreads();
    for (int jj = 0; jj < 7; ++jj) {
        int j = blockIdx.y * 28 + jj * 4 + (t >> 6);
        if (j < NN) {
            float a = bl[j];
#pragma unroll 2
            for (int k = 0; k < NN; ++k)
                a += Wl[j * NN + k] * zs[k * 64 + c];   // Wl wave-uniform -> scalar
            out[(size_t)j * C + c0 + c] = a;
        }
    }
}

// ---------------------------------------------------------------------------
extern "C" void kernel_launch(void* const* d_in, const int* in_sizes, int n_in,
                              void* d_out, int out_size, void* d_ws, size_t ws_size,
                              hipStream_t stream) {
    const float* x   = (const float*)d_in[0];
    const int*   adj = (const int*)d_in[1];
    const float* W2  = (const float*)d_in[2];
    const float* b2  = (const float*)d_in[3];
    const float* W1  = (const float*)d_in[4];
    const float* b1  = (const float*)d_in[5];
    const float* Wl  = (const float*)d_in[6];
    const float* bl  = (const float*)d_in[7];
    float* out = (float*)d_out;

    char* ws = (char*)d_ws;
    float*    hpart = (float*)(ws);                    // 8 x 110*4096 f32 = 14417920 B
    float*    zpart = (float*)(ws + 14417920);         // 8 x 110*4096 f32 = 14417920 B
    float*    z_raw = (float*)(ws + 28835840);         // 110*4096 f32    = 1802240 B
    _Float16* A1t   = (_Float16*)(ws + 30638080);      // 112*4096 f16 frag-major
    _Float16* A3t   = (_Float16*)(ws + 31555584);      // 112*8192 f16 frag-major
    ull*      mlo   = (ull*)(ws + 33390592);           // 110 u64
    ull*      mhi   = (ull*)(ws + 33391472);           // 110 u64
    float*    degs  = (float*)(ws + 33392352);         // 110 f32

    // no memset needed: all buffers fully overwritten each call
    prep1_kernel<<<225, 256, 0, stream>>>(x, A1t, adj, mlo, mhi, degs);
    mm_kernel<8><<<dim3(64, NSLICE), 256, 0, stream>>>(A1t, W2, hpart);
    agg_kernel<<<C / 16, 256, 0, stream>>>(hpart, mlo, mhi, degs, b2, A3t);
    mm_kernel<16><<<dim3(64, NSLICE), 256, 0, stream>>>(A3t, W1, zpart);
    zred_kernel<<<440, 256, 0, stream>>>(zpart, z_raw);
    fin_kernel<<<dim3(C / 64, 4), 256, 0, stream>>>(z_raw, b1, Wl, bl, out);
}